// Round 1
// baseline (51.313 us; speedup 1.0000x reference)
//
#include <hip/hip_runtime.h>
#include <math.h>

#define NN 64
#define DD 128
#define HH 256

// ws layout (floats):
//   P  [64][256] @ 0        (P = x @ cdW1[0:128]   + cdb1)
//   Q  [64][256] @ 16384    (Q = x @ cdW1[128:256])
//   A  [64][256] @ 32768    (A = x @ cfW1[0:128]   + cfb1)
//   B  [64][256] @ 49152    (B = x @ cfW1[128:256])
//   C4 [64 d4][64 k][4] @ 65536   (C = x @ cfW1[256:384], transposed for coalesced k-lane loads)
// total 81920 floats = 320 KB

__global__ __launch_bounds__(256) void k_proj(
    const float* __restrict__ x, const int* __restrict__ inode,
    const float* __restrict__ cdW1, const float* __restrict__ cdb1,
    const float* __restrict__ cfW1, const float* __restrict__ cfb1,
    float* __restrict__ ws, float* __restrict__ out3)
{
    __shared__ float xs[DD];
    const int n = blockIdx.x;
    const int c = threadIdx.x;
    if (c < DD) xs[c] = x[n * DD + c];
    __syncthreads();

    float accP = 0.f, accQ = 0.f, accA = 0.f, accB = 0.f, accC = 0.f;
#pragma unroll 4
    for (int d = 0; d < DD; ++d) {
        const float xv = xs[d];
        accP += xv * cdW1[d * HH + c];
        accQ += xv * cdW1[(DD + d) * HH + c];
        accA += xv * cfW1[d * HH + c];
        accB += xv * cfW1[(DD + d) * HH + c];
        accC += xv * cfW1[(2 * DD + d) * HH + c];
    }
    float* P  = ws;
    float* Q  = ws + 16384;
    float* A  = ws + 32768;
    float* B  = ws + 49152;
    float* C4 = ws + 65536;
    P[n * HH + c] = accP + cdb1[c];
    Q[n * HH + c] = accQ;
    A[n * HH + c] = accA + cfb1[c];
    B[n * HH + c] = accB;
    C4[((c >> 2) * NN + n) * 4 + (c & 3)] = accC;

    // modified_features: copy untouched rows
    const int node = inode[0];
    if (n != node && c < DD) out3[n * DD + c] = x[n * DD + c];
}

__global__ __launch_bounds__(256) void k_intervene(
    const float* __restrict__ x, const int* __restrict__ inode,
    const float* __restrict__ ival,
    const float* __restrict__ ipW1, const float* __restrict__ ipb1,
    const float* __restrict__ ipW2, const float* __restrict__ ipb2,
    float* __restrict__ out3)
{
    __shared__ float in_s[DD + 1];
    __shared__ float h_s[HH];
    const int t = threadIdx.x;
    const int node = inode[0];
    if (t < DD) in_s[t] = x[node * DD + t];
    if (t == DD) in_s[DD] = ival[0];
    __syncthreads();

    float acc = ipb1[t];
    for (int d = 0; d < DD + 1; ++d) acc += in_s[d] * ipW1[d * HH + t];
    h_s[t] = fmaxf(acc, 0.f);
    __syncthreads();

    if (t < DD) {
        float a2 = ipb2[t];
        for (int u = 0; u < HH; ++u) a2 += h_s[u] * ipW2[u * DD + t];
        out3[node * DD + t] = a2;  // no relu on output layer
    }
}

// causal: per (i,j): h1 = relu(P[i]+Q[j]); h2 = relu(h1 @ cdW2 + cdb2);
//         sigmoid(h2 . cdW3 + cdb3), diag = 0
__global__ __launch_bounds__(256) void k_pairs(
    const float* __restrict__ ws, const float* __restrict__ cdW2,
    const float* __restrict__ cdb2, const float* __restrict__ cdW3,
    const float* __restrict__ cdb3, float* __restrict__ causal)
{
    const float* P = ws;
    const float* Q = ws + 16384;
    __shared__ float W2s[HH * 128];   // 128 KB, [t][c]
    __shared__ float h1s[16 * HH];    // 16 KB, [jj][t]
    const int i  = blockIdx.x >> 2;
    const int j0 = (blockIdx.x & 3) * 16;
    const int tid = threadIdx.x;

    // stage cdW2 -> LDS (coalesced float4)
    {
        const float4* src = (const float4*)cdW2;
        float4* dst = (float4*)W2s;
        for (int u = tid; u < HH * 128 / 4; u += 256) dst[u] = src[u];
    }
    // h1 tile: thread = t
    {
        const float pv = P[i * HH + tid];
#pragma unroll
        for (int jj = 0; jj < 16; ++jj) {
            h1s[jj * HH + tid] = fmaxf(pv + Q[(j0 + jj) * HH + tid], 0.f);
        }
    }
    __syncthreads();

    const int c4 = tid & 31;   // owns columns c4*4 .. c4*4+3
    const int jp = tid >> 5;   // 0..7
    const float4* W2v = (const float4*)W2s;
    const float4 b2 = ((const float4*)cdb2)[c4];
    const float4 w3 = ((const float4*)cdW3)[c4];
    const float b3 = cdb3[0];

    for (int pass = 0; pass < 2; ++pass) {
        const int jj = pass * 8 + jp;
        const float4* h1v = (const float4*)(&h1s[jj * HH]);
        float4 acc = {0.f, 0.f, 0.f, 0.f};
#pragma unroll 8
        for (int t4 = 0; t4 < HH / 4; ++t4) {
            const float4 h4 = h1v[t4];  // broadcast (2 addrs/wave)
            const float4 wa = W2v[(t4 * 4 + 0) * 32 + c4];
            const float4 wb = W2v[(t4 * 4 + 1) * 32 + c4];
            const float4 wc = W2v[(t4 * 4 + 2) * 32 + c4];
            const float4 wd = W2v[(t4 * 4 + 3) * 32 + c4];
            acc.x += h4.x * wa.x + h4.y * wb.x + h4.z * wc.x + h4.w * wd.x;
            acc.y += h4.x * wa.y + h4.y * wb.y + h4.z * wc.y + h4.w * wd.y;
            acc.z += h4.x * wa.z + h4.y * wb.z + h4.z * wc.z + h4.w * wd.z;
            acc.w += h4.x * wa.w + h4.y * wb.w + h4.z * wc.w + h4.w * wd.w;
        }
        const float h2x = fmaxf(acc.x + b2.x, 0.f);
        const float h2y = fmaxf(acc.y + b2.y, 0.f);
        const float h2z = fmaxf(acc.z + b2.z, 0.f);
        const float h2w = fmaxf(acc.w + b2.w, 0.f);
        float partial = h2x * w3.x + h2y * w3.y + h2z * w3.z + h2w * w3.w;
#pragma unroll
        for (int m = 16; m >= 1; m >>= 1) partial += __shfl_xor(partial, m, 64);
        if (c4 == 0) {
            const float z = partial + b3;
            const float sg = 1.f / (1.f + expf(-z));
            const int j = j0 + jj;
            causal[i * NN + j] = (i == j) ? 0.f : sg;
        }
    }
}

// confounder: per (i,j,k): sigmoid( sum_d max(A[i][d]+B[j][d]+C[k][d],0)*cfW2[d] + cfb2 )
__global__ __launch_bounds__(256) void k_triple(
    const float* __restrict__ ws, const float* __restrict__ cfW2,
    const float* __restrict__ cfb2, float* __restrict__ conf)
{
    const float* A  = ws + 32768;
    const float* B  = ws + 49152;
    const float* C4 = ws + 65536;
    __shared__ float s_s[16 * HH];   // 16 KB: s[jj][d] = A[i][d] + B[j0+jj][d]
    const int i  = blockIdx.x >> 2;
    const int j0 = (blockIdx.x & 3) * 16;
    const int tid = threadIdx.x;

    for (int u = tid; u < 16 * HH; u += 256) {
        const int jj = u >> 8, d = u & 255;
        s_s[u] = A[i * HH + d] + B[(j0 + jj) * HH + d];
    }
    __syncthreads();

    const int k   = tid & 63;
    const int jj2 = tid >> 6;    // 0..3
    float acc[4] = {0.f, 0.f, 0.f, 0.f};
    const float4* C4v = (const float4*)C4;   // [d4*64 + k]
    const float4* sv  = (const float4*)s_s;  // [jj*64 + d4]
    const float4* w2g = (const float4*)cfW2; // uniform -> scalar loads

    for (int ch = 0; ch < 4; ++ch) {
        float4 cr[16], wr[16];
#pragma unroll
        for (int q = 0; q < 16; ++q) {
            cr[q] = C4v[(ch * 16 + q) * 64 + k];  // coalesced across k-lanes
            wr[q] = w2g[ch * 16 + q];             // wave-uniform
        }
#pragma unroll
        for (int p = 0; p < 4; ++p) {
            const int jj = p * 4 + jj2;
            float a = acc[p];
#pragma unroll
            for (int q = 0; q < 16; ++q) {
                const float4 s4 = sv[jj * 64 + ch * 16 + q];  // LDS broadcast
                a += fmaxf(s4.x + cr[q].x, 0.f) * wr[q].x;
                a += fmaxf(s4.y + cr[q].y, 0.f) * wr[q].y;
                a += fmaxf(s4.z + cr[q].z, 0.f) * wr[q].z;
                a += fmaxf(s4.w + cr[q].w, 0.f) * wr[q].w;
            }
            acc[p] = a;
        }
    }
    const float b2 = cfb2[0];
#pragma unroll
    for (int p = 0; p < 4; ++p) {
        const int j = j0 + p * 4 + jj2;
        const float z = acc[p] + b2;
        const float sg = 1.f / (1.f + expf(-z));
        const bool distinct = (i != j) && (j != k) && (i != k);
        conf[(i * NN + j) * NN + k] = distinct ? sg : 0.f;
    }
}

extern "C" void kernel_launch(void* const* d_in, const int* in_sizes, int n_in,
                              void* d_out, int out_size, void* d_ws, size_t ws_size,
                              hipStream_t stream) {
    const float* x    = (const float*)d_in[0];
    const int*   node = (const int*)d_in[1];
    const float* ival = (const float*)d_in[2];
    const float* cdW1 = (const float*)d_in[3];
    const float* cdb1 = (const float*)d_in[4];
    const float* cdW2 = (const float*)d_in[5];
    const float* cdb2 = (const float*)d_in[6];
    const float* cdW3 = (const float*)d_in[7];
    const float* cdb3 = (const float*)d_in[8];
    const float* cfW1 = (const float*)d_in[9];
    const float* cfb1 = (const float*)d_in[10];
    const float* cfW2 = (const float*)d_in[11];
    const float* cfb2 = (const float*)d_in[12];
    const float* ipW1 = (const float*)d_in[13];
    const float* ipb1 = (const float*)d_in[14];
    const float* ipW2 = (const float*)d_in[15];
    const float* ipb2 = (const float*)d_in[16];

    float* out    = (float*)d_out;
    float* causal = out;                      // 4096
    float* conf   = out + NN * NN;            // 262144
    float* out3   = out + NN * NN + NN * NN * NN;  // 8192
    float* wsf    = (float*)d_ws;

    k_proj<<<dim3(64), dim3(256), 0, stream>>>(x, node, cdW1, cdb1, cfW1, cfb1, wsf, out3);
    k_intervene<<<dim3(1), dim3(256), 0, stream>>>(x, node, ival, ipW1, ipb1, ipW2, ipb2, out3);
    k_pairs<<<dim3(256), dim3(256), 0, stream>>>(wsf, cdW2, cdb2, cdW3, cdb3, causal);
    k_triple<<<dim3(256), dim3(256), 0, stream>>>(wsf, cfW2, cfb2, conf);
}

// Round 2
// 36.134 us; speedup vs baseline: 1.4201x; 1.4201x over previous
//
#include <hip/hip_runtime.h>
#include <math.h>

#define NN 64
#define DD 128
#define HH 256

// ws layout (floats):
//   P  [64][256] @ 0        (x @ cdW1[0:128]   + cdb1)
//   Q  [64][256] @ 16384    (x @ cdW1[128:256])
//   A  [64][256] @ 32768    (x @ cfW1[0:128]   + cfb1)
//   B  [64][256] @ 49152    (x @ cfW1[128:256])
//   C4 [64 d4][64 k]float4 @ 65536  (x @ cfW1[256:384], transposed)

// Kernel A: grid 321. Blocks 0..319: projection p=bid>>6 for node n=bid&63.
// Block 320: intervention MLP. Also copies modified_features rows.
__global__ __launch_bounds__(256) void k_stage(
    const float* __restrict__ x, const int* __restrict__ inode,
    const float* __restrict__ ival,
    const float* __restrict__ cdW1, const float* __restrict__ cdb1,
    const float* __restrict__ cfW1, const float* __restrict__ cfb1,
    const float* __restrict__ ipW1, const float* __restrict__ ipb1,
    const float* __restrict__ ipW2, const float* __restrict__ ipb2,
    float* __restrict__ ws, float* __restrict__ out3)
{
    const int bid = blockIdx.x;
    const int tid = threadIdx.x;
    if (bid < 320) {
        __shared__ float xs[DD];
        __shared__ float4 red[4][64];
        const int p = bid >> 6;
        const int n = bid & 63;
        if (tid < DD) xs[tid] = x[n * DD + tid];
        __syncthreads();
        const int c4 = tid & 63;   // float4 column group (cols c4*4..c4*4+3)
        const int dg = tid >> 6;   // d-quarter
        const float* Wp = (p == 0) ? cdW1
                        : (p == 1) ? (cdW1 + DD * HH)
                                   : (cfW1 + (p - 2) * DD * HH);
        const float4* Wp4 = (const float4*)Wp;   // rows of 64 float4
        float4 acc = {0.f, 0.f, 0.f, 0.f};
#pragma unroll 8
        for (int r = 0; r < 32; ++r) {
            const int d = dg * 32 + r;
            const float xv = xs[d];
            const float4 w = Wp4[d * 64 + c4];
            acc.x += xv * w.x; acc.y += xv * w.y;
            acc.z += xv * w.z; acc.w += xv * w.w;
        }
        red[dg][c4] = acc;
        __syncthreads();
        const int node = inode[0];
        if (tid < 64) {
            const float4 r0 = red[0][tid], r1 = red[1][tid];
            const float4 r2 = red[2][tid], r3 = red[3][tid];
            float4 s;
            s.x = r0.x + r1.x + r2.x + r3.x;
            s.y = r0.y + r1.y + r2.y + r3.y;
            s.z = r0.z + r1.z + r2.z + r3.z;
            s.w = r0.w + r1.w + r2.w + r3.w;
            if (p == 0) {
                const float4 b = ((const float4*)cdb1)[tid];
                s.x += b.x; s.y += b.y; s.z += b.z; s.w += b.w;
                ((float4*)(ws))[n * 64 + tid] = s;
            } else if (p == 1) {
                ((float4*)(ws + 16384))[n * 64 + tid] = s;
            } else if (p == 2) {
                const float4 b = ((const float4*)cfb1)[tid];
                s.x += b.x; s.y += b.y; s.z += b.z; s.w += b.w;
                ((float4*)(ws + 32768))[n * 64 + tid] = s;
            } else if (p == 3) {
                ((float4*)(ws + 49152))[n * 64 + tid] = s;
            } else {
                ((float4*)(ws + 65536))[tid * 64 + n] = s;  // C4[d4][n]
            }
        }
        if (p == 0 && tid >= 64 && tid < 192) {
            if (n != node) out3[n * DD + (tid - 64)] = xs[tid - 64];
        }
    } else {
        // intervention MLP: [x[node], v] (129) -> relu 256 -> 128
        __shared__ float in_s[DD + 1];
        __shared__ float h_s[HH];
        const int node = inode[0];
        if (tid < DD) in_s[tid] = x[node * DD + tid];
        if (tid == DD) in_s[DD] = ival[0];
        __syncthreads();
        float acc = ipb1[tid];
#pragma unroll 4
        for (int d = 0; d < DD + 1; ++d) acc += in_s[d] * ipW1[d * HH + tid];
        h_s[tid] = fmaxf(acc, 0.f);
        __syncthreads();
        if (tid < DD) {
            float a2 = ipb2[tid];
#pragma unroll 4
            for (int u = 0; u < HH; ++u) a2 += h_s[u] * ipW2[u * DD + tid];
            out3[node * DD + tid] = a2;
        }
    }
}

// Kernel B: grid 512. bid<256: pair unit (i=bid>>2, j0=(bid&3)*16).
//                     bid>=256: triple unit (same decomposition).
// smem = 80 KB -> 2 blocks/CU, so pairs and triple blocks co-reside.
__global__ __launch_bounds__(256) void k_pt(
    const float* __restrict__ ws,
    const float* __restrict__ cdW2, const float* __restrict__ cdb2,
    const float* __restrict__ cdW3, const float* __restrict__ cdb3,
    const float* __restrict__ cfW2, const float* __restrict__ cfb2,
    float* __restrict__ causal, float* __restrict__ conf)
{
    __shared__ float smem[20480];  // 80 KB
    const int bid = blockIdx.x;
    const int tid = threadIdx.x;
    if (bid < 256) {
        // ---- causal pairs: h2 = relu(h1 @ cdW2 + b2); sigmoid(h2.cdW3 + b3)
        const float* P = ws;
        const float* Q = ws + 16384;
        float* W2s = smem;            // 16384 floats: half of cdW2 (128 rows)
        float* h1s = smem + 16384;    // 4096 floats: h1[16][256]
        const int i  = bid >> 2;
        const int j0 = (bid & 3) * 16;

        {   // stage W2 rows 0..127
            const float4* src = (const float4*)cdW2;
            float4* dst = (float4*)W2s;
#pragma unroll
            for (int u = 0; u < 16; ++u) dst[tid + u * 256] = src[tid + u * 256];
        }
        {   // h1 tile
            const float pv = P[i * HH + tid];
#pragma unroll
            for (int jj = 0; jj < 16; ++jj)
                h1s[jj * HH + tid] = fmaxf(pv + Q[(j0 + jj) * HH + tid], 0.f);
        }
        __syncthreads();

        const int c4 = tid & 31;   // owns cols c4*4..+3
        const int jp = tid >> 5;   // 0..7; thread does jj=jp and jj=jp+8
        const float4* W2v = (const float4*)W2s;
        const float4* hav = (const float4*)(h1s + jp * HH);
        const float4* hbv = (const float4*)(h1s + (jp + 8) * HH);
        float4 acc0 = {0.f,0.f,0.f,0.f}, acc1 = {0.f,0.f,0.f,0.f};

#pragma unroll 4
        for (int t4 = 0; t4 < 32; ++t4) {
            const float4 wa = W2v[(t4 * 4 + 0) * 32 + c4];
            const float4 wb = W2v[(t4 * 4 + 1) * 32 + c4];
            const float4 wc = W2v[(t4 * 4 + 2) * 32 + c4];
            const float4 wd = W2v[(t4 * 4 + 3) * 32 + c4];
            const float4 ha = hav[t4];
            const float4 hb = hbv[t4];
            acc0.x += ha.x*wa.x + ha.y*wb.x + ha.z*wc.x + ha.w*wd.x;
            acc0.y += ha.x*wa.y + ha.y*wb.y + ha.z*wc.y + ha.w*wd.y;
            acc0.z += ha.x*wa.z + ha.y*wb.z + ha.z*wc.z + ha.w*wd.z;
            acc0.w += ha.x*wa.w + ha.y*wb.w + ha.z*wc.w + ha.w*wd.w;
            acc1.x += hb.x*wa.x + hb.y*wb.x + hb.z*wc.x + hb.w*wd.x;
            acc1.y += hb.x*wa.y + hb.y*wb.y + hb.z*wc.y + hb.w*wd.y;
            acc1.z += hb.x*wa.z + hb.y*wb.z + hb.z*wc.z + hb.w*wd.z;
            acc1.w += hb.x*wa.w + hb.y*wb.w + hb.z*wc.w + hb.w*wd.w;
        }
        __syncthreads();
        {   // stage W2 rows 128..255
            const float4* src = (const float4*)cdW2 + 4096;
            float4* dst = (float4*)W2s;
#pragma unroll
            for (int u = 0; u < 16; ++u) dst[tid + u * 256] = src[tid + u * 256];
        }
        __syncthreads();
#pragma unroll 4
        for (int t4 = 0; t4 < 32; ++t4) {
            const float4 wa = W2v[(t4 * 4 + 0) * 32 + c4];
            const float4 wb = W2v[(t4 * 4 + 1) * 32 + c4];
            const float4 wc = W2v[(t4 * 4 + 2) * 32 + c4];
            const float4 wd = W2v[(t4 * 4 + 3) * 32 + c4];
            const float4 ha = hav[t4 + 32];
            const float4 hb = hbv[t4 + 32];
            acc0.x += ha.x*wa.x + ha.y*wb.x + ha.z*wc.x + ha.w*wd.x;
            acc0.y += ha.x*wa.y + ha.y*wb.y + ha.z*wc.y + ha.w*wd.y;
            acc0.z += ha.x*wa.z + ha.y*wb.z + ha.z*wc.z + ha.w*wd.z;
            acc0.w += ha.x*wa.w + ha.y*wb.w + ha.z*wc.w + ha.w*wd.w;
            acc1.x += hb.x*wa.x + hb.y*wb.x + hb.z*wc.x + hb.w*wd.x;
            acc1.y += hb.x*wa.y + hb.y*wb.y + hb.z*wc.y + hb.w*wd.y;
            acc1.z += hb.x*wa.z + hb.y*wb.z + hb.z*wc.z + hb.w*wd.z;
            acc1.w += hb.x*wa.w + hb.y*wb.w + hb.z*wc.w + hb.w*wd.w;
        }

        const float4 b2 = ((const float4*)cdb2)[c4];
        const float4 w3 = ((const float4*)cdW3)[c4];
        const float  b3 = cdb3[0];
        float pr0 = fmaxf(acc0.x + b2.x, 0.f) * w3.x + fmaxf(acc0.y + b2.y, 0.f) * w3.y
                  + fmaxf(acc0.z + b2.z, 0.f) * w3.z + fmaxf(acc0.w + b2.w, 0.f) * w3.w;
        float pr1 = fmaxf(acc1.x + b2.x, 0.f) * w3.x + fmaxf(acc1.y + b2.y, 0.f) * w3.y
                  + fmaxf(acc1.z + b2.z, 0.f) * w3.z + fmaxf(acc1.w + b2.w, 0.f) * w3.w;
#pragma unroll
        for (int m = 16; m >= 1; m >>= 1) {
            pr0 += __shfl_xor(pr0, m, 64);
            pr1 += __shfl_xor(pr1, m, 64);
        }
        if (c4 == 0) {
            const int ja = j0 + jp, jb = j0 + jp + 8;
            const float sa = 1.f / (1.f + expf(-(pr0 + b3)));
            const float sb = 1.f / (1.f + expf(-(pr1 + b3)));
            causal[i * NN + ja] = (i == ja) ? 0.f : sa;
            causal[i * NN + jb] = (i == jb) ? 0.f : sb;
        }
    } else {
        // ---- confounder triples: sigmoid(sum_d relu(A_i+B_j+C_k)*w2 + b2)
        const int u = bid - 256;
        const float* A  = ws + 32768;
        const float* B  = ws + 49152;
        const float* C4 = ws + 65536;
        float* s_s = smem;          // 4096 floats: s[jj][d] = A[i]+B[j0+jj]
        float* w2s = smem + 4096;   // 256 floats: cfW2
        const int i  = u >> 2;
        const int j0 = (u & 3) * 16;
        for (int v = tid; v < 16 * HH; v += 256) {
            const int jj = v >> 8, d = v & 255;
            s_s[v] = A[i * HH + d] + B[(j0 + jj) * HH + d];
        }
        if (tid < 64) ((float4*)w2s)[tid] = ((const float4*)cfW2)[tid];
        __syncthreads();

        const int k   = tid & 63;
        const int jj2 = tid >> 6;
        float acc[4] = {0.f, 0.f, 0.f, 0.f};
        const float4* C4v = (const float4*)C4;
        const float4* sv  = (const float4*)s_s;
        const float4* wv  = (const float4*)w2s;
        for (int ch = 0; ch < 8; ++ch) {
            float4 cr[8], wr[8];
#pragma unroll
            for (int q = 0; q < 8; ++q) {
                cr[q] = C4v[(ch * 8 + q) * 64 + k];   // coalesced over k-lanes
                wr[q] = wv[ch * 8 + q];               // LDS broadcast
            }
#pragma unroll
            for (int p = 0; p < 4; ++p) {
                const int jj = p * 4 + jj2;
                float a = acc[p];
#pragma unroll
                for (int q = 0; q < 8; ++q) {
                    const float4 s4 = sv[jj * 64 + ch * 8 + q];  // broadcast
                    a += fmaxf(s4.x + cr[q].x, 0.f) * wr[q].x;
                    a += fmaxf(s4.y + cr[q].y, 0.f) * wr[q].y;
                    a += fmaxf(s4.z + cr[q].z, 0.f) * wr[q].z;
                    a += fmaxf(s4.w + cr[q].w, 0.f) * wr[q].w;
                }
                acc[p] = a;
            }
        }
        const float b2 = cfb2[0];
#pragma unroll
        for (int p = 0; p < 4; ++p) {
            const int j = j0 + p * 4 + jj2;
            const float z = acc[p] + b2;
            const float sg = 1.f / (1.f + expf(-z));
            const bool distinct = (i != j) && (j != k) && (i != k);
            conf[(i * NN + j) * NN + k] = distinct ? sg : 0.f;
        }
    }
}

extern "C" void kernel_launch(void* const* d_in, const int* in_sizes, int n_in,
                              void* d_out, int out_size, void* d_ws, size_t ws_size,
                              hipStream_t stream) {
    const float* x    = (const float*)d_in[0];
    const int*   node = (const int*)d_in[1];
    const float* ival = (const float*)d_in[2];
    const float* cdW1 = (const float*)d_in[3];
    const float* cdb1 = (const float*)d_in[4];
    const float* cdW2 = (const float*)d_in[5];
    const float* cdb2 = (const float*)d_in[6];
    const float* cdW3 = (const float*)d_in[7];
    const float* cdb3 = (const float*)d_in[8];
    const float* cfW1 = (const float*)d_in[9];
    const float* cfb1 = (const float*)d_in[10];
    const float* cfW2 = (const float*)d_in[11];
    const float* cfb2 = (const float*)d_in[12];
    const float* ipW1 = (const float*)d_in[13];
    const float* ipb1 = (const float*)d_in[14];
    const float* ipW2 = (const float*)d_in[15];
    const float* ipb2 = (const float*)d_in[16];

    float* out    = (float*)d_out;
    float* causal = out;                           // 4096
    float* conf   = out + NN * NN;                 // 262144
    float* out3   = out + NN * NN + NN * NN * NN;  // 8192
    float* wsf    = (float*)d_ws;

    k_stage<<<dim3(321), dim3(256), 0, stream>>>(
        x, node, ival, cdW1, cdb1, cfW1, cfb1, ipW1, ipb1, ipW2, ipb2, wsf, out3);
    k_pt<<<dim3(512), dim3(256), 0, stream>>>(
        wsf, cdW2, cdb2, cdW3, cdb3, cfW2, cfb2, causal, conf);
}